// Round 2
// baseline (161.467 us; speedup 1.0000x reference)
//
#include <hip/hip_runtime.h>
#include <hip/hip_bf16.h>

#define NTOT 16384
#define NP   8192
#define NQ   8192
#define DIM  128

typedef float f32x4 __attribute__((ext_vector_type(4)));
typedef __bf16 bf16x8 __attribute__((ext_vector_type(8)));

__device__ __forceinline__ float wave_reduce_sum(float v) {
#pragma unroll
    for (int off = 32; off > 0; off >>= 1)
        v += __shfl_xor(v, off, 64);
    return v;
}

// ---------------------------------------------------------------------------
// Kernel A: per-row separable sums + bf16 packing of the GEMM operands.
//   positives (rows 0..NP-1):   rowPack[i] = (1 - sP[i], 2*t1[i]),  pv[i][d] = bf16(mu*varA)
//   negatives (rows NP..N-1):   colPack[j] = (sN[j],    2*t2[j]),  nb[j][d] = bf16(mu)
// One wave per row; lane handles 2 dims.
// ---------------------------------------------------------------------------
__global__ __launch_bounds__(256)
void ptl_prep(const float* __restrict__ means,
              const float* __restrict__ vars,
              __hip_bfloat16* __restrict__ pv,
              __hip_bfloat16* __restrict__ nb,
              float2* __restrict__ rowPack,
              float2* __restrict__ colPack)
{
    const int wid  = threadIdx.x >> 6;
    const int lane = threadIdx.x & 63;
    const int r    = (blockIdx.x << 2) + wid;
    const int d    = lane << 1;

    const float2 mu   = *reinterpret_cast<const float2*>(means + (size_t)r * DIM + d);
    const float2 var  = *reinterpret_cast<const float2*>(vars  + (size_t)r * DIM + d);
    const float2 muA  = *reinterpret_cast<const float2*>(means + d);
    const float2 varA = *reinterpret_cast<const float2*>(vars  + d);

    float s = 0.f, t = 0.f;
    {
        const float m = mu.x, v = var.x, ma = muA.x, va = varA.x;
        const float m2 = m * m, ma2 = ma * ma;
        s += m2 + v - 2.f * ma * m;
        t += v * v + 2.f * m2 * v + 2.f * (va + ma2) * (v + m2)
           - 2.f * ma2 * m2 - 4.f * ma * m * v;
    }
    {
        const float m = mu.y, v = var.y, ma = muA.y, va = varA.y;
        const float m2 = m * m, ma2 = ma * ma;
        s += m2 + v - 2.f * ma * m;
        t += v * v + 2.f * m2 * v + 2.f * (va + ma2) * (v + m2)
           - 2.f * ma2 * m2 - 4.f * ma * m * v;
    }
    s = wave_reduce_sum(s);
    t = wave_reduce_sum(t);

    if (r < NP) {
        __hip_bfloat162 pb;
        pb.x = __float2bfloat16(mu.x * varA.x);
        pb.y = __float2bfloat16(mu.y * varA.y);
        *reinterpret_cast<__hip_bfloat162*>(pv + (size_t)r * DIM + d) = pb;
        if (lane == 0) rowPack[r] = make_float2(1.f - s, 2.f * t);
    } else {
        const int q = r - NP;
        __hip_bfloat162 qb;
        qb.x = __float2bfloat16(mu.x);
        qb.y = __float2bfloat16(mu.y);
        *reinterpret_cast<__hip_bfloat162*>(nb + (size_t)q * DIM + d) = qb;
        if (lane == 0) colPack[q] = make_float2(s, 2.f * t);
    }
}

// ---------------------------------------------------------------------------
// Kernel B: tiled cross-GEMM (bf16 MFMA, K=128) + fused epilogue + reduction.
// 128x128 output tile per block; 4 waves each own a 64x64 quadrant (4x4
// fragments of 16x16x32). Fragments loaded directly from global (L2-resident).
// C layout (verified, m89): col = lane&15, row = (lane>>4)*4 + reg.
// ---------------------------------------------------------------------------
__global__ __launch_bounds__(256)
void ptl_main(const __hip_bfloat16* __restrict__ pv,
              const __hip_bfloat16* __restrict__ nb,
              const float2* __restrict__ rowPack,
              const float2* __restrict__ colPack,
              const float* __restrict__ nmul,
              float* __restrict__ out)
{
    const int wid  = threadIdx.x >> 6;
    const int lane = threadIdx.x & 63;
    const int bi   = blockIdx.x >> 6;
    const int bj   = blockIdx.x & 63;
    const int wr   = wid >> 1, wc = wid & 1;
    const int i0   = bi * 128 + wr * 64;
    const int j0   = bj * 128 + wc * 64;
    const int l16  = lane & 15;
    const int l4   = lane >> 4;

    f32x4 acc[4][4];
#pragma unroll
    for (int m = 0; m < 4; ++m)
#pragma unroll
        for (int n = 0; n < 4; ++n)
            acc[m][n] = (f32x4){0.f, 0.f, 0.f, 0.f};

    const __hip_bfloat16* Ab = pv + (size_t)(i0 + l16) * DIM + l4 * 8;
    const __hip_bfloat16* Bb = nb + (size_t)(j0 + l16) * DIM + l4 * 8;

#pragma unroll
    for (int kq = 0; kq < 4; ++kq) {
        bf16x8 a[4], b[4];
#pragma unroll
        for (int m = 0; m < 4; ++m)
            a[m] = *reinterpret_cast<const bf16x8*>(Ab + m * 16 * DIM + kq * 32);
#pragma unroll
        for (int n = 0; n < 4; ++n)
            b[n] = *reinterpret_cast<const bf16x8*>(Bb + n * 16 * DIM + kq * 32);
#pragma unroll
        for (int m = 0; m < 4; ++m)
#pragma unroll
            for (int n = 0; n < 4; ++n)
                acc[m][n] = __builtin_amdgcn_mfma_f32_16x16x32_bf16(a[m], b[n], acc[m][n], 0, 0, 0);
    }

    float2 cp[4];
#pragma unroll
    for (int n = 0; n < 4; ++n)
        cp[n] = colPack[j0 + n * 16 + l16];

    float lacc0 = 0.f, lacc1 = 0.f, lacc2 = 0.f, lacc3 = 0.f;
#pragma unroll
    for (int m = 0; m < 4; ++m) {
        float2 rp[4];
#pragma unroll
        for (int rr = 0; rr < 4; ++rr)
            rp[rr] = rowPack[i0 + m * 16 + l4 * 4 + rr];
#pragma unroll
        for (int n = 0; n < 4; ++n) {
#pragma unroll
            for (int rr = 0; rr < 4; ++rr) {
                const float c   = acc[m][n][rr];
                const float t12 = rp[rr].y + cp[n].y;          // 2*t1 + 2*t2
                const float omm = rp[rr].x + cp[n].x;          // 1 - mu
                float s2 = fmaf(-8.f, c, t12);
                s2 = fmaxf(s2, 1e-16f);                        // clip + rsqrt guard
                const float inv_sigma = __builtin_amdgcn_rsqf(s2);
                const float z  = omm * inv_sigma * 0.7071067811865475f;
                const float az = fabsf(z);
                // Abramowitz-Stegun 7.1.26: erfc(az) = poly(t)*exp(-az^2), |err|<=1.5e-7
                const float tt = __builtin_amdgcn_rcpf(fmaf(0.3275911f, az, 1.f));
                float poly = fmaf(tt, 1.061405429f, -1.453152027f);
                poly = fmaf(tt, poly, 1.421413741f);
                poly = fmaf(tt, poly, -0.284496736f);
                poly = fmaf(tt, poly, 0.254829592f);
                poly *= tt;
                const float e = __expf(-az * az);
                const float erfc_ = poly * e;
                const float probs = (z >= 0.f) ? fmaf(-0.5f, erfc_, 1.f) : 0.5f * erfc_;
                const float lg = __logf(probs + 1e-8f);
                if (rr == 0) lacc0 += lg;
                else if (rr == 1) lacc1 += lg;
                else if (rr == 2) lacc2 += lg;
                else lacc3 += lg;
            }
        }
    }

    float lsum = (lacc0 + lacc1) + (lacc2 + lacc3);
    lsum = wave_reduce_sum(lsum);

    __shared__ float wsum[4];
    if (lane == 0) wsum[wid] = lsum;
    __syncthreads();
    if (threadIdx.x == 0) {
        const float bsum = (wsum[0] + wsum[1]) + (wsum[2] + wsum[3]);
        const float cst = nmul[0] / (0.5f * (float)NP * (float)NQ);
        atomicAdd(out, -cst * bsum);
    }
}

extern "C" void kernel_launch(void* const* d_in, const int* in_sizes, int n_in,
                              void* d_out, int out_size, void* d_ws, size_t ws_size,
                              hipStream_t stream)
{
    const float* means = (const float*)d_in[1];   // est_means [N, D] f32
    const float* vars  = (const float*)d_in[2];   // est_vars  [N, D] f32
    const float* nmul  = (const float*)d_in[3];   // NmulPnN scalar f32
    float* out = (float*)d_out;

    __hip_bfloat16* pv = (__hip_bfloat16*)d_ws;                 // [NP,128] bf16 (2 MB)
    __hip_bfloat16* nb = pv + (size_t)NP * DIM;                 // [NQ,128] bf16 (2 MB)
    float2* rowPack = (float2*)((char*)d_ws + (size_t)(NP + NQ) * DIM * sizeof(__hip_bfloat16));
    float2* colPack = rowPack + NP;

    hipMemsetAsync(d_out, 0, sizeof(float), stream);
    ptl_prep<<<NTOT / 4, 256, 0, stream>>>(means, vars, pv, nb, rowPack, colPack);
    ptl_main<<<(NP / 128) * (NQ / 128), 256, 0, stream>>>(pv, nb, rowPack, colPack, nmul, out);
}

// Round 4
// 159.131 us; speedup vs baseline: 1.0147x; 1.0147x over previous
//
#include <hip/hip_runtime.h>
#include <hip/hip_bf16.h>
#include <math.h>

#define NTOT 16384
#define NP   8192
#define NQ   8192
#define DIM  128
#define TBLN 2048              // LUT entries over x in [-8, 8]
#define TBL_SCALE 128.0f       // entries per unit x
#define INV_SQRT2 0.70710678118654752f

typedef float f32x4 __attribute__((ext_vector_type(4)));
typedef __bf16 bf16x8 __attribute__((ext_vector_type(8)));

__device__ __forceinline__ float wave_reduce_sum(float v) {
#pragma unroll
    for (int off = 32; off > 0; off >>= 1)
        v += __shfl_xor(v, off, 64);
    return v;
}

// round-to-nearest-even f32 -> bf16 bits (unbiased; avoids truncation bias)
__device__ __forceinline__ unsigned short f32_to_bf16_rne(float f) {
    unsigned u = __float_as_uint(f);
    u += 0x7FFFu + ((u >> 16) & 1u);
    return (unsigned short)(u >> 16);
}

// ---------------------------------------------------------------------------
// Kernel A: per-row separable sums + bf16 packing of the GEMM operands.
//   positives (rows 0..NP-1): rowPack[i] = (1 - sP[i], 2*t1[i]), pv[i][d]=bf16(mu*varA)
//   negatives (rows NP..N-1): colPack[j] = (sN[j],    2*t2[j]), nb[j][d]=bf16(mu)
// Blocks 0..7 additionally build the 2048-entry LUT of
//   g(x) = -ln(0.5*erfc(-x/sqrt2) + 1e-8), packed (bf16 g | bf16 dg) per u32.
// ---------------------------------------------------------------------------
__global__ __launch_bounds__(256)
void ptl_prep(const float* __restrict__ means,
              const float* __restrict__ vars,
              __hip_bfloat16* __restrict__ pv,
              __hip_bfloat16* __restrict__ nb,
              float2* __restrict__ rowPack,
              float2* __restrict__ colPack,
              unsigned* __restrict__ tblG)
{
    const int wid  = threadIdx.x >> 6;
    const int lane = threadIdx.x & 63;
    const int r    = (blockIdx.x << 2) + wid;
    const int d    = lane << 1;

    const float2 mu   = *reinterpret_cast<const float2*>(means + (size_t)r * DIM + d);
    const float2 var  = *reinterpret_cast<const float2*>(vars  + (size_t)r * DIM + d);
    const float2 muA  = *reinterpret_cast<const float2*>(means + d);
    const float2 varA = *reinterpret_cast<const float2*>(vars  + d);

    float s = 0.f, t = 0.f;
    {
        const float m = mu.x, v = var.x, ma = muA.x, va = varA.x;
        const float m2 = m * m, ma2 = ma * ma;
        s += m2 + v - 2.f * ma * m;
        t += v * v + 2.f * m2 * v + 2.f * (va + ma2) * (v + m2)
           - 2.f * ma2 * m2 - 4.f * ma * m * v;
    }
    {
        const float m = mu.y, v = var.y, ma = muA.y, va = varA.y;
        const float m2 = m * m, ma2 = ma * ma;
        s += m2 + v - 2.f * ma * m;
        t += v * v + 2.f * m2 * v + 2.f * (va + ma2) * (v + m2)
           - 2.f * ma2 * m2 - 4.f * ma * m * v;
    }
    s = wave_reduce_sum(s);
    t = wave_reduce_sum(t);

    if (r < NP) {
        __hip_bfloat162 pb;
        pb.x = __float2bfloat16(mu.x * varA.x);
        pb.y = __float2bfloat16(mu.y * varA.y);
        *reinterpret_cast<__hip_bfloat162*>(pv + (size_t)r * DIM + d) = pb;
        if (lane == 0) rowPack[r] = make_float2(1.f - s, 2.f * t);
    } else {
        const int q = r - NP;
        __hip_bfloat162 qb;
        qb.x = __float2bfloat16(mu.x);
        qb.y = __float2bfloat16(mu.y);
        *reinterpret_cast<__hip_bfloat162*>(nb + (size_t)q * DIM + d) = qb;
        if (lane == 0) colPack[q] = make_float2(s, 2.f * t);
    }

    // LUT build (accurate path, runs once; 2048 threads total)
    if (blockIdx.x < 8) {
        const int k = blockIdx.x * 256 + threadIdx.x;      // 0..2047
        const float x0 = -8.f + (float)k / TBL_SCALE;
        const float x1 = -8.f + (float)(k + 1) / TBL_SCALE;
        const float g0 = -logf(0.5f * erfcf(-x0 * INV_SQRT2) + 1e-8f);
        const float g1 = -logf(0.5f * erfcf(-x1 * INV_SQRT2) + 1e-8f);
        const unsigned short gb = f32_to_bf16_rne(g0);
        const unsigned short db = f32_to_bf16_rne(g1 - g0);
        tblG[k] = ((unsigned)db << 16) | (unsigned)gb;
    }
}

// ---------------------------------------------------------------------------
// Kernel B: cross-GEMM (bf16 MFMA, K=128) + LUT epilogue + reduction.
// 128x128 tile/block; 4 waves each own 64x64 (4x4 frags of 16x16x32).
// Epilogue: s2 = 2t1+2t2-8c; x = (1-mu)*rsq(s2); g via LDS LUT lerp.
// LUT duplicated x2 in LDS, lane-parity copy select (bank-conflict relief).
// ---------------------------------------------------------------------------
__global__ __launch_bounds__(256)
void ptl_main(const __hip_bfloat16* __restrict__ pv,
              const __hip_bfloat16* __restrict__ nb,
              const float2* __restrict__ rowPack,
              const float2* __restrict__ colPack,
              const unsigned* __restrict__ tblG,
              const float* __restrict__ nmul,
              float* __restrict__ out)
{
    const int wid  = threadIdx.x >> 6;
    const int lane = threadIdx.x & 63;
    const int bi   = blockIdx.x >> 6;
    const int bj   = blockIdx.x & 63;
    const int wr   = wid >> 1, wc = wid & 1;
    const int i0   = bi * 128 + wr * 64;
    const int j0   = bj * 128 + wc * 64;
    const int l16  = lane & 15;
    const int l4   = lane >> 4;

    __shared__ unsigned tbl[2 * TBLN];
    {
        const uint4* gt4 = (const uint4*)tblG;
        uint4* lt4 = (uint4*)tbl;
#pragma unroll
        for (int t = threadIdx.x; t < TBLN / 4; t += 256) {
            const uint4 v = gt4[t];
            lt4[t] = v;
            lt4[t + TBLN / 4] = v;
        }
    }
    __syncthreads();

    f32x4 acc[4][4];
#pragma unroll
    for (int m = 0; m < 4; ++m)
#pragma unroll
        for (int n = 0; n < 4; ++n)
            acc[m][n] = (f32x4){0.f, 0.f, 0.f, 0.f};

    const __hip_bfloat16* Ab = pv + (size_t)(i0 + l16) * DIM + l4 * 8;
    const __hip_bfloat16* Bb = nb + (size_t)(j0 + l16) * DIM + l4 * 8;

#pragma unroll
    for (int kq = 0; kq < 4; ++kq) {
        bf16x8 a[4], b[4];
#pragma unroll
        for (int m = 0; m < 4; ++m)
            a[m] = *reinterpret_cast<const bf16x8*>(Ab + m * 16 * DIM + kq * 32);
#pragma unroll
        for (int n = 0; n < 4; ++n)
            b[n] = *reinterpret_cast<const bf16x8*>(Bb + n * 16 * DIM + kq * 32);
#pragma unroll
        for (int m = 0; m < 4; ++m)
#pragma unroll
            for (int n = 0; n < 4; ++n)
                acc[m][n] = __builtin_amdgcn_mfma_f32_16x16x32_bf16(a[m], b[n], acc[m][n], 0, 0, 0);
    }

    float2 cp[4];
#pragma unroll
    for (int n = 0; n < 4; ++n)
        cp[n] = colPack[j0 + n * 16 + l16];

    const unsigned laneSel = ((unsigned)lane & 1u) << 11;   // copy select (u32 index)

    float lacc0 = 0.f, lacc1 = 0.f, lacc2 = 0.f, lacc3 = 0.f;
#pragma unroll
    for (int m = 0; m < 4; ++m) {
        float2 rp[4];
#pragma unroll
        for (int rr = 0; rr < 4; ++rr)
            rp[rr] = rowPack[i0 + m * 16 + l4 * 4 + rr];
#pragma unroll
        for (int n = 0; n < 4; ++n) {
#pragma unroll
            for (int rr = 0; rr < 4; ++rr) {
                const float c   = acc[m][n][rr];
                const float t12 = rp[rr].y + cp[n].y;        // 2t1 + 2t2
                const float omm = rp[rr].x + cp[n].x;        // 1 - mu
                float s2 = fmaf(-8.f, c, t12);               // sigma^2
                s2 = fmaxf(s2, 1e-20f);
                const float x = omm * __builtin_amdgcn_rsqf(s2);
                float u = fmaf(x, TBL_SCALE, 1024.0f);       // (x+8)*128
                u = __builtin_amdgcn_fmed3f(u, 0.0f, 2047.999f);
                const unsigned iu = (unsigned)u;
                const float fr = u - (float)iu;
                const unsigned pk = tbl[iu + laneSel];
                const float g  = __uint_as_float(pk << 16);          // bf16 lo -> f32
                const float dg = __uint_as_float(pk & 0xFFFF0000u);  // bf16 hi -> f32
                const float val = fmaf(fr, dg, g);
                if (rr == 0) lacc0 += val;
                else if (rr == 1) lacc1 += val;
                else if (rr == 2) lacc2 += val;
                else lacc3 += val;
            }
        }
    }

    float lsum = (lacc0 + lacc1) + (lacc2 + lacc3);
    lsum = wave_reduce_sum(lsum);

    __shared__ float wsum[4];
    if (lane == 0) wsum[wid] = lsum;
    __syncthreads();
    if (threadIdx.x == 0) {
        const float bsum = (wsum[0] + wsum[1]) + (wsum[2] + wsum[3]);
        const float cst = nmul[0] / (0.5f * (float)NP * (float)NQ);
        atomicAdd(out, cst * bsum);    // g already = -log(probs+eps)
    }
}

extern "C" void kernel_launch(void* const* d_in, const int* in_sizes, int n_in,
                              void* d_out, int out_size, void* d_ws, size_t ws_size,
                              hipStream_t stream)
{
    const float* means = (const float*)d_in[1];   // est_means [N, D] f32
    const float* vars  = (const float*)d_in[2];   // est_vars  [N, D] f32
    const float* nmul  = (const float*)d_in[3];   // NmulPnN scalar f32
    float* out = (float*)d_out;

    __hip_bfloat16* pv = (__hip_bfloat16*)d_ws;                 // [NP,128] bf16 (2 MB)
    __hip_bfloat16* nb = pv + (size_t)NP * DIM;                 // [NQ,128] bf16 (2 MB)
    float2* rowPack = (float2*)((char*)d_ws + (size_t)(NP + NQ) * DIM * sizeof(__hip_bfloat16));
    float2* colPack = rowPack + NP;
    unsigned* tblG  = (unsigned*)(colPack + NQ);                // [2048] u32 (8 KB)

    hipMemsetAsync(d_out, 0, sizeof(float), stream);
    ptl_prep<<<NTOT / 4, 256, 0, stream>>>(means, vars, pv, nb, rowPack, colPack, tblG);
    ptl_main<<<(NP / 128) * (NQ / 128), 256, 0, stream>>>(pv, nb, rowPack, colPack, tblG, nmul, out);
}

// Round 5
// 149.779 us; speedup vs baseline: 1.0780x; 1.0624x over previous
//
#include <hip/hip_runtime.h>
#include <hip/hip_bf16.h>
#include <math.h>

#define NTOT 16384
#define NP   8192
#define NQ   8192
#define DIM  128
#define TBLN 4096              // LUT cells over x in [-8, 8]
#define TBL_SCALE 256.0f       // cells per unit x
#define INV_SQRT2 0.70710678118654752f

typedef float f32x4 __attribute__((ext_vector_type(4)));
typedef __bf16 bf16x8 __attribute__((ext_vector_type(8)));

__device__ __forceinline__ float wave_reduce_sum(float v) {
#pragma unroll
    for (int off = 32; off > 0; off >>= 1)
        v += __shfl_xor(v, off, 64);
    return v;
}

// ---------------------------------------------------------------------------
// Kernel A: per-row separable sums + bf16 packing of the GEMM operands.
//   positives (rows 0..NP-1): rowPack[i] = (1 - sP[i], 2*t1[i]), pv[i][d]=bf16(mu*varA)
//   negatives (rows NP..N-1): colPack[j] = (sN[j],    2*t2[j]), nb[j][d]=bf16(mu)
// Blocks 0..15 build the 4096-entry f32 LUT of g at CELL CENTERS:
//   g(x) = -ln(0.5*erfc(-x/sqrt2) + 1e-8)   (nearest-cell lookup, no lerp)
// Block 0 thread 0 zeroes the output accumulator (replaces hipMemsetAsync).
// ---------------------------------------------------------------------------
__global__ __launch_bounds__(256)
void ptl_prep(const float* __restrict__ means,
              const float* __restrict__ vars,
              __hip_bfloat16* __restrict__ pv,
              __hip_bfloat16* __restrict__ nb,
              float2* __restrict__ rowPack,
              float2* __restrict__ colPack,
              float* __restrict__ tblG,
              float* __restrict__ out)
{
    const int wid  = threadIdx.x >> 6;
    const int lane = threadIdx.x & 63;
    const int r    = (blockIdx.x << 2) + wid;
    const int d    = lane << 1;

    if (blockIdx.x == 0 && threadIdx.x == 0) out[0] = 0.f;

    const float2 mu   = *reinterpret_cast<const float2*>(means + (size_t)r * DIM + d);
    const float2 var  = *reinterpret_cast<const float2*>(vars  + (size_t)r * DIM + d);
    const float2 muA  = *reinterpret_cast<const float2*>(means + d);
    const float2 varA = *reinterpret_cast<const float2*>(vars  + d);

    float s = 0.f, t = 0.f;
    {
        const float m = mu.x, v = var.x, ma = muA.x, va = varA.x;
        const float m2 = m * m, ma2 = ma * ma;
        s += m2 + v - 2.f * ma * m;
        t += v * v + 2.f * m2 * v + 2.f * (va + ma2) * (v + m2)
           - 2.f * ma2 * m2 - 4.f * ma * m * v;
    }
    {
        const float m = mu.y, v = var.y, ma = muA.y, va = varA.y;
        const float m2 = m * m, ma2 = ma * ma;
        s += m2 + v - 2.f * ma * m;
        t += v * v + 2.f * m2 * v + 2.f * (va + ma2) * (v + m2)
           - 2.f * ma2 * m2 - 4.f * ma * m * v;
    }
    s = wave_reduce_sum(s);
    t = wave_reduce_sum(t);

    if (r < NP) {
        __hip_bfloat162 pb;
        pb.x = __float2bfloat16(mu.x * varA.x);
        pb.y = __float2bfloat16(mu.y * varA.y);
        *reinterpret_cast<__hip_bfloat162*>(pv + (size_t)r * DIM + d) = pb;
        if (lane == 0) rowPack[r] = make_float2(1.f - s, 2.f * t);
    } else {
        const int q = r - NP;
        __hip_bfloat162 qb;
        qb.x = __float2bfloat16(mu.x);
        qb.y = __float2bfloat16(mu.y);
        *reinterpret_cast<__hip_bfloat162*>(nb + (size_t)q * DIM + d) = qb;
        if (lane == 0) colPack[q] = make_float2(s, 2.f * t);
    }

    if (blockIdx.x < 16) {
        const int k = blockIdx.x * 256 + threadIdx.x;      // 0..4095
        const float xc = -8.f + ((float)k + 0.5f) / TBL_SCALE;   // cell center
        tblG[k] = -logf(0.5f * erfcf(-xc * INV_SQRT2) + 1e-8f);
    }
}

// ---------------------------------------------------------------------------
// Kernel B: cross-GEMM (bf16 MFMA, K=128) + batched-gather LUT epilogue.
// 128x128 tile/block; 4 waves each own 64x64 (4x4 frags of 16x16x32).
// Epilogue per m-quadrant (16 elems): phase A computes 16 indices, phase B
// issues 16 INDEPENDENT ds_read_b32 gathers (MLP — kills the latency
// serialization seen in round 4: VALUBusy 36%, nothing saturated), phase C
// accumulates. LUT x2 replicated, lane-parity select.
// ---------------------------------------------------------------------------
__global__ __launch_bounds__(256, 4)
void ptl_main(const __hip_bfloat16* __restrict__ pv,
              const __hip_bfloat16* __restrict__ nb,
              const float2* __restrict__ rowPack,
              const float2* __restrict__ colPack,
              const float* __restrict__ tblG,
              const float* __restrict__ nmul,
              float* __restrict__ out)
{
    const int wid  = threadIdx.x >> 6;
    const int lane = threadIdx.x & 63;
    const int bi   = blockIdx.x >> 6;
    const int bj   = blockIdx.x & 63;
    const int wr   = wid >> 1, wc = wid & 1;
    const int i0   = bi * 128 + wr * 64;
    const int j0   = bj * 128 + wc * 64;
    const int l16  = lane & 15;
    const int l4   = lane >> 4;

    __shared__ float tbl[2 * TBLN];
    {
        const float4* g4 = (const float4*)tblG;
        float4* l4p = (float4*)tbl;
#pragma unroll
        for (int t = threadIdx.x; t < TBLN / 4; t += 256) {
            const float4 v = g4[t];
            l4p[t] = v;
            l4p[t + TBLN / 4] = v;
        }
    }
    __syncthreads();

    f32x4 acc[4][4];
#pragma unroll
    for (int m = 0; m < 4; ++m)
#pragma unroll
        for (int n = 0; n < 4; ++n)
            acc[m][n] = (f32x4){0.f, 0.f, 0.f, 0.f};

    const __hip_bfloat16* Ab = pv + (size_t)(i0 + l16) * DIM + l4 * 8;
    const __hip_bfloat16* Bb = nb + (size_t)(j0 + l16) * DIM + l4 * 8;

#pragma unroll
    for (int kq = 0; kq < 4; ++kq) {
        bf16x8 a[4], b[4];
#pragma unroll
        for (int m = 0; m < 4; ++m)
            a[m] = *reinterpret_cast<const bf16x8*>(Ab + m * 16 * DIM + kq * 32);
#pragma unroll
        for (int n = 0; n < 4; ++n)
            b[n] = *reinterpret_cast<const bf16x8*>(Bb + n * 16 * DIM + kq * 32);
#pragma unroll
        for (int m = 0; m < 4; ++m)
#pragma unroll
            for (int n = 0; n < 4; ++n)
                acc[m][n] = __builtin_amdgcn_mfma_f32_16x16x32_bf16(a[m], b[n], acc[m][n], 0, 0, 0);
    }

    float2 cp[4];
#pragma unroll
    for (int n = 0; n < 4; ++n)
        cp[n] = colPack[j0 + n * 16 + l16];

    const unsigned laneSel = ((unsigned)lane & 1u) << 12;   // copy stride 4096 (f32 idx)

    float lacc0 = 0.f, lacc1 = 0.f, lacc2 = 0.f, lacc3 = 0.f;
#pragma unroll
    for (int m = 0; m < 4; ++m) {
        float2 rp[4];
#pragma unroll
        for (int rr = 0; rr < 4; ++rr)
            rp[rr] = rowPack[i0 + m * 16 + l4 * 4 + rr];

        // Phase A: 16 LUT indices (as clamped f32)
        float us[16];
#pragma unroll
        for (int n = 0; n < 4; ++n) {
#pragma unroll
            for (int rr = 0; rr < 4; ++rr) {
                const float c   = acc[m][n][rr];
                const float t12 = rp[rr].y + cp[n].y;        // 2t1 + 2t2
                const float omm = rp[rr].x + cp[n].x;        // 1 - mu
                float s2 = fmaf(-8.f, c, t12);               // sigma^2
                s2 = fmaxf(s2, 1e-20f);
                const float x = omm * __builtin_amdgcn_rsqf(s2);
                float u = fmaf(x, TBL_SCALE, 2048.0f);       // (x+8)*256
                us[n * 4 + rr] = __builtin_amdgcn_fmed3f(u, 0.0f, 4095.99f);
            }
        }

        // Phase B: 16 independent LDS gathers (in flight together)
        float pk[16];
#pragma unroll
        for (int e = 0; e < 16; ++e)
            pk[e] = tbl[(unsigned)us[e] + laneSel];

        // Phase C: accumulate (4 chains)
#pragma unroll
        for (int e = 0; e < 16; e += 4) {
            lacc0 += pk[e];
            lacc1 += pk[e + 1];
            lacc2 += pk[e + 2];
            lacc3 += pk[e + 3];
        }
    }

    float lsum = (lacc0 + lacc1) + (lacc2 + lacc3);
    lsum = wave_reduce_sum(lsum);

    __shared__ float wsum[4];
    if (lane == 0) wsum[wid] = lsum;
    __syncthreads();
    if (threadIdx.x == 0) {
        const float bsum = (wsum[0] + wsum[1]) + (wsum[2] + wsum[3]);
        const float cst = nmul[0] / (0.5f * (float)NP * (float)NQ);
        atomicAdd(out, cst * bsum);    // g already = -log(probs+eps)
    }
}

extern "C" void kernel_launch(void* const* d_in, const int* in_sizes, int n_in,
                              void* d_out, int out_size, void* d_ws, size_t ws_size,
                              hipStream_t stream)
{
    const float* means = (const float*)d_in[1];   // est_means [N, D] f32
    const float* vars  = (const float*)d_in[2];   // est_vars  [N, D] f32
    const float* nmul  = (const float*)d_in[3];   // NmulPnN scalar f32
    float* out = (float*)d_out;

    __hip_bfloat16* pv = (__hip_bfloat16*)d_ws;                 // [NP,128] bf16 (2 MB)
    __hip_bfloat16* nb = pv + (size_t)NP * DIM;                 // [NQ,128] bf16 (2 MB)
    float2* rowPack = (float2*)((char*)d_ws + (size_t)(NP + NQ) * DIM * sizeof(__hip_bfloat16));
    float2* colPack = rowPack + NP;
    float* tblG     = (float*)(colPack + NQ);                   // [4096] f32 (16 KB)

    ptl_prep<<<NTOT / 4, 256, 0, stream>>>(means, vars, pv, nb, rowPack, colPack, tblG, out);
    ptl_main<<<(NP / 128) * (NQ / 128), 256, 0, stream>>>(pv, nb, rowPack, colPack, tblG, nmul, out);
}